// Round 1
// baseline (264.417 us; speedup 1.0000x reference)
//
#include <hip/hip_runtime.h>

// BahdanauAttention with seq-len == 1:
//   softmax over a length-1 axis is identically 1.0, so
//     attention_weights == ones((B,1,1))
//     context           == features  (exact copy)
// The W1/W2/V GEMMs are dead code. Optimal kernel = HBM copy + constant fill.

#define BB 16384
#define DD 2048

// out layout (flat, fp32): [ context: BB*DD ][ attention_weights: BB ]
// N4_ctx = BB*DD/4 float4 copies, then BB/4 float4 ones-writes.

__global__ __launch_bounds__(256) void bahdanau_seqlen1_kernel(
    const float4* __restrict__ feat4, float4* __restrict__ out4) {
    const unsigned N4_ctx = (unsigned)(BB * DD / 4);       // 8,388,608
    const unsigned N4_tot = N4_ctx + (unsigned)(BB / 4);   // + 4,096
    unsigned i = blockIdx.x * blockDim.x + threadIdx.x;
    if (i >= N4_tot) return;
    if (i < N4_ctx) {
        out4[i] = feat4[i];                 // context = features
    } else {
        out4[i] = make_float4(1.f, 1.f, 1.f, 1.f);  // attention_weights = 1
    }
}

extern "C" void kernel_launch(void* const* d_in, const int* in_sizes, int n_in,
                              void* d_out, int out_size, void* d_ws, size_t ws_size,
                              hipStream_t stream) {
    const float* features = (const float*)d_in[0];   // (B, D) fp32
    float* out = (float*)d_out;                      // context (B*D) ++ weights (B)

    const unsigned N4_tot = (unsigned)((BB * DD + BB) / 4); // 8,392,704
    const int threads = 256;
    const unsigned blocks = (N4_tot + threads - 1) / threads; // 32,784

    bahdanau_seqlen1_kernel<<<dim3(blocks), dim3(threads), 0, stream>>>(
        (const float4*)features, (float4*)out);
}